// Round 6
// baseline (267.603 us; speedup 1.0000x reference)
//
#include <hip/hip_runtime.h>

typedef __bf16 bf16x8 __attribute__((ext_vector_type(8)));
typedef __bf16 bf16x4 __attribute__((ext_vector_type(4)));
typedef float  f32x4  __attribute__((ext_vector_type(4)));

__device__ __forceinline__ f32x4 mfma_bf16(bf16x8 a, bf16x8 b, f32x4 c) {
  return __builtin_amdgcn_mfma_f32_16x16x32_bf16(a, b, c, 0, 0, 0);
}
// Packed B-fragment load: Bp[((kt*NT+nt)*64+lane)*8 .. +7]
__device__ __forceinline__ bf16x8 ldB(const __bf16* Bp, int kt, int NT, int nt,
                                      int lane) {
  return *reinterpret_cast<const bf16x8*>(Bp + (((size_t)kt * NT + nt) * 64 + lane) * 8);
}
__device__ __forceinline__ bf16x8 cvt8(float4 a, float4 b) {
  bf16x8 v;
  v[0] = (__bf16)a.x; v[1] = (__bf16)a.y; v[2] = (__bf16)a.z; v[3] = (__bf16)a.w;
  v[4] = (__bf16)b.x; v[5] = (__bf16)b.y; v[6] = (__bf16)b.z; v[7] = (__bf16)b.w;
  return v;
}

// Grid barrier -- ONLY for tiny grids (<= ~40 blocks). R4 lesson: full-grid
// spin barriers (512 blocks) cost ~100s of microseconds.
__device__ __forceinline__ void gridbar(int* cnt, int target) {
  __syncthreads();
  if (threadIdx.x == 0) {
    __threadfence();
    __hip_atomic_fetch_add(cnt, 1, __ATOMIC_RELEASE, __HIP_MEMORY_SCOPE_AGENT);
    while (__hip_atomic_load(cnt, __ATOMIC_RELAXED, __HIP_MEMORY_SCOPE_AGENT) < target)
      __builtin_amdgcn_s_sleep(4);
    __threadfence();
  }
  __syncthreads();
}

// ---------------------------------------------------------------------------
// All weight packs in ONE kernel + zero G + zero gridbar counter.
// ---------------------------------------------------------------------------
__global__ void pack_all(const float* __restrict__ W1, const float* __restrict__ W2,
                         const float* __restrict__ Wg1, const float* __restrict__ Wg2,
                         const float* __restrict__ Wr1, const float* __restrict__ Wr2,
                         __bf16* __restrict__ W1p, __bf16* __restrict__ W2p,
                         __bf16* __restrict__ Wg1p, __bf16* __restrict__ Wg2p,
                         __bf16* __restrict__ Wr1p, __bf16* __restrict__ Wr2p,
                         float* __restrict__ G, int* __restrict__ cnt) {
  int bx = blockIdx.x;
  int lane = threadIdx.x;
  if (bx >= 1104) {  // zero G (256x256 f32): 32 blocks x 64 thr x 8 float4
    if (bx == 1104 && lane == 0) cnt[0] = 0;  // small_pair barrier counter
    float4* g = (float4*)G;
    int base = (bx - 1104) * 512 + lane;
#pragma unroll
    for (int i = 0; i < 8; ++i) g[base + i * 64] = make_float4(0.f, 0.f, 0.f, 0.f);
    return;
  }
  const float* W; __bf16* out; int N, K, NT, local;
  if (bx < 544)      { W = W1;  out = W1p;  N = 256; K = 1080; NT = 16; local = bx; }
  else if (bx < 672) { W = W2;  out = W2p;  N = 256; K = 256;  NT = 16; local = bx - 544; }
  else if (bx < 784) { W = Wg1; out = Wg1p; N = 256; K = 200;  NT = 16; local = bx - 672; }
  else if (bx < 848) { W = Wg2; out = Wg2p; N = 128; K = 256;  NT = 8;  local = bx - 784; }
  else if (bx < 912) { W = Wr1; out = Wr1p; N = 256; K = 128;  NT = 16; local = bx - 848; }
  else               { W = Wr2; out = Wr2p; N = 360; K = 256;  NT = 24; local = bx - 912; }
  int nt = local % NT, kt = local / NT;
  int n = nt * 16 + (lane & 15);
  int k0 = kt * 32 + (lane >> 4) * 8;
  bf16x8 v;
#pragma unroll
  for (int e = 0; e < 8; ++e) {
    int k = k0 + e;
    float xv = (n < N && k < K) ? W[(size_t)n * K + k] : 0.f;
    v[e] = (__bf16)xv;
  }
  *reinterpret_cast<bf16x8*>(out + ((size_t)local * 64 + lane) * 8) = v;
}

// ---------------------------------------------------------------------------
// Fused surrogate v2: h1 A-operand loaded DIRECTLY from global (32B/lane
// contiguous, L2-served) -> ZERO barriers in the 34-step K-loop. Masks are
// transposed through LDS (mskT) then stored as 64B-contiguous runs (4x16B per
// column) instead of 2B scatters. Tile 32x256, 4 waves, grid 512.
// ---------------------------------------------------------------------------
__global__ __launch_bounds__(256) void h1h2_fused(
    const float* __restrict__ x, const __bf16* __restrict__ W1p,
    const float* __restrict__ b1, const __bf16* __restrict__ W2p,
    const float* __restrict__ b2, __bf16* __restrict__ m1T,
    __bf16* __restrict__ m2T) {
  __shared__ __bf16 h1s[32][264];    // relu(h1), stride 528B (2-way banks, free)
  __shared__ __bf16 mskT[256][40];   // mask transpose buf; stride 80B (16B-mult)
  int tid = threadIdx.x;
  int lane = tid & 63, wid = tid >> 6;
  int rowBase = blockIdx.x * 32;
  int q4 = (lane >> 4) * 4;
  int kg = (lane >> 4) * 8;
  const float* a0p = x + (size_t)(rowBase + (lane & 15)) * 1080;
  const float* a1p = a0p + (size_t)16 * 1080;
  f32x4 acc[2][4] = {};
#pragma unroll 2
  for (int kt = 0; kt < 34; ++kt) {
    int k0 = kt * 32 + kg;
    bf16x8 a0, a1;
    if (k0 < 1080) {  // only lane-group 3 at kt=33 is out of range (k0==1080)
      float4 x0 = *(const float4*)(a0p + k0);
      float4 x1 = *(const float4*)(a0p + k0 + 4);
      float4 y0 = *(const float4*)(a1p + k0);
      float4 y1 = *(const float4*)(a1p + k0 + 4);
      a0 = cvt8(x0, x1);
      a1 = cvt8(y0, y1);
    } else {
#pragma unroll
      for (int e = 0; e < 8; ++e) { a0[e] = (__bf16)0.f; a1[e] = (__bf16)0.f; }
    }
#pragma unroll
    for (int n = 0; n < 4; ++n) {
      bf16x8 bv = ldB(W1p, kt, 16, wid * 4 + n, lane);
      acc[0][n] = mfma_bf16(a0, bv, acc[0][n]);
      acc[1][n] = mfma_bf16(a1, bv, acc[1][n]);
    }
  }
  // ---- h1 epilogue: m1 -> mskT (LDS transpose), relu(h1) -> h1s ----
#pragma unroll
  for (int m = 0; m < 2; ++m)
#pragma unroll
    for (int n = 0; n < 4; ++n) {
      int col = wid * 64 + n * 16 + (lane & 15);
      float bb = b1[col];
#pragma unroll
      for (int j = 0; j < 4; ++j) {
        int rl = m * 16 + q4 + j;
        float h = acc[m][n][j] + bb;
        mskT[col][rl] = (__bf16)(h > 0.f ? 1.f : 0.f);
        h1s[rl][col] = (__bf16)fmaxf(h, 0.f);
      }
    }
  __syncthreads();
  // ---- m1 store pass: thread t owns column t; 64B contiguous run ----
  {
    __bf16* dst = m1T + (size_t)tid * 16384 + rowBase;
#pragma unroll
    for (int i = 0; i < 4; ++i)
      *reinterpret_cast<bf16x8*>(dst + i * 8) =
          *reinterpret_cast<const bf16x8*>(&mskT[tid][i * 8]);
  }
  // ---- h2 phase: K=256 from LDS (barrier-free) ----
  f32x4 acc2[2][4] = {};
#pragma unroll
  for (int ks = 0; ks < 8; ++ks) {
    int arow = lane & 15, ak = ks * 32 + (lane >> 4) * 8;
    bf16x8 a0 = *reinterpret_cast<const bf16x8*>(&h1s[arow][ak]);
    bf16x8 a1 = *reinterpret_cast<const bf16x8*>(&h1s[arow + 16][ak]);
#pragma unroll
    for (int n = 0; n < 4; ++n) {
      bf16x8 bv = ldB(W2p, ks, 16, wid * 4 + n, lane);
      acc2[0][n] = mfma_bf16(a0, bv, acc2[0][n]);
      acc2[1][n] = mfma_bf16(a1, bv, acc2[1][n]);
    }
  }
  __syncthreads();  // all m1-store mskT reads complete before overwrite
#pragma unroll
  for (int m = 0; m < 2; ++m)
#pragma unroll
    for (int n = 0; n < 4; ++n) {
      int col = wid * 64 + n * 16 + (lane & 15);
      float bb = b2[col];
#pragma unroll
      for (int j = 0; j < 4; ++j) {
        int rl = m * 16 + q4 + j;
        float h = acc2[m][n][j] + bb;
        mskT[col][rl] = (__bf16)(h > 0.f ? 1.f : 0.f);
      }
    }
  __syncthreads();
  // ---- m2 store pass ----
  {
    __bf16* dst = m2T + (size_t)tid * 16384 + rowBase;
#pragma unroll
    for (int i = 0; i < 4; ++i)
      *reinterpret_cast<bf16x8*>(dst + i * 8) =
          *reinterpret_cast<const bf16x8*>(&mskT[tid][i * 8]);
  }
}

// ---------------------------------------------------------------------------
// Streaming masks GEMM: G += (1/B) * m2[chunk]^T @ m1[chunk].
// Transposed mask layout -> direct contiguous bf16x8 loads; no LDS/barriers.
// Partial tiles are exact dyadic rationals -> atomicAdd is exact & determin.
// ---------------------------------------------------------------------------
__global__ __launch_bounds__(256) void gemm_masks(
    const __bf16* __restrict__ m2T, const __bf16* __restrict__ m1T,
    float* __restrict__ G) {
  int tid = threadIdx.x;
  int lane = tid & 63, wid = tid >> 6;
  int wr = wid >> 1, wc = wid & 1;
  int ibase = blockIdx.x * 64, jbase = blockIdx.y * 64;
  size_t b0 = (size_t)blockIdx.z * 1024 + (lane >> 4) * 8;
  const __bf16* pa0 = m2T + (size_t)(ibase + wr * 32 + (lane & 15)) * 16384 + b0;
  const __bf16* pa1 = pa0 + (size_t)16 * 16384;
  const __bf16* pb0 = m1T + (size_t)(jbase + wc * 32 + (lane & 15)) * 16384 + b0;
  const __bf16* pb1 = pb0 + (size_t)16 * 16384;
  f32x4 acc[2][2] = {};
#pragma unroll 4
  for (int c = 0; c < 32; ++c) {
    bf16x8 a0 = *reinterpret_cast<const bf16x8*>(pa0 + c * 32);
    bf16x8 a1 = *reinterpret_cast<const bf16x8*>(pa1 + c * 32);
    bf16x8 bv0 = *reinterpret_cast<const bf16x8*>(pb0 + c * 32);
    bf16x8 bv1 = *reinterpret_cast<const bf16x8*>(pb1 + c * 32);
    acc[0][0] = mfma_bf16(a0, bv0, acc[0][0]);
    acc[0][1] = mfma_bf16(a0, bv1, acc[0][1]);
    acc[1][0] = mfma_bf16(a1, bv0, acc[1][0]);
    acc[1][1] = mfma_bf16(a1, bv1, acc[1][1]);
  }
  int q4 = (lane >> 4) * 4;
#pragma unroll
  for (int m = 0; m < 2; ++m)
#pragma unroll
    for (int n = 0; n < 2; ++n)
#pragma unroll
      for (int j = 0; j < 4; ++j) {
        int gi = ibase + wr * 32 + m * 16 + q4 + j;
        int gj = jbase + wc * 32 + n * 16 + (lane & 15);
        atomicAdd(&G[(size_t)gi * 256 + gj], acc[m][n][j] * (1.f / 16384.f));
      }
}

// ---------------------------------------------------------------------------
// 64x64-tile f32 GEMM body (256 threads): C[MxN] = (A .* A2) @ B
// ---------------------------------------------------------------------------
__device__ void small_body(float (*As)[17], float (*Bs)[65], int t,
                           const float* __restrict__ A, const float* __restrict__ A2,
                           int lda, const float* __restrict__ Bm, int ldb,
                           float* __restrict__ C, int ldc,
                           int M, int N, int K, int m0, int n0) {
  int tx = t & 15, ty = t >> 4;
  float acc[4][4] = {};
  for (int k0 = 0; k0 < K; k0 += 16) {
#pragma unroll
    for (int i = 0; i < 4; ++i) {
      int idx = t * 4 + i;
      int r = idx >> 4, kk = idx & 15;
      int gm = m0 + r, gk = k0 + kk;
      float v = (gm < M && gk < K) ? A[(size_t)gm * lda + gk] : 0.f;
      if (A2 && gm < M && gk < K) v *= A2[(size_t)gm * lda + gk];
      As[r][kk] = v;
      int kk2 = idx >> 6, cc = idx & 63;
      int gk2 = k0 + kk2, gn = n0 + cc;
      Bs[kk2][cc] = (gk2 < K && gn < N) ? Bm[(size_t)gk2 * ldb + gn] : 0.f;
    }
    __syncthreads();
#pragma unroll
    for (int kk = 0; kk < 16; ++kk)
#pragma unroll
      for (int i = 0; i < 4; ++i)
#pragma unroll
        for (int j = 0; j < 4; ++j)
          acc[i][j] += As[ty * 4 + i][kk] * Bs[kk][tx * 4 + j];
    __syncthreads();
  }
#pragma unroll
  for (int i = 0; i < 4; ++i)
#pragma unroll
    for (int j = 0; j < 4; ++j) {
      int gm = m0 + ty * 4 + i, gn = n0 + tx * 4 + j;
      if (gm < M && gn < N) C[(size_t)gm * ldc + gn] = acc[i][j];
    }
}

// ---------------------------------------------------------------------------
// small_pair: T = (W2 .* G) @ W1[:, -360:] (24 tiles) | gridbar(36) | ec = W3@T
// ---------------------------------------------------------------------------
__global__ __launch_bounds__(256) void small_pair(
    const float* __restrict__ W2, const float* __restrict__ G,
    const float* __restrict__ W1, const float* __restrict__ W3,
    float* __restrict__ T, float* __restrict__ o_ec, int* __restrict__ cnt) {
  __shared__ float As[64][17];
  __shared__ float Bs[16][65];
  int t = threadIdx.x, bid = blockIdx.x;
  if (bid < 24)
    small_body(As, Bs, t, W2, G, 256, W1 + 720, 1080, T, 384,
               256, 360, 256, (bid / 6) * 64, (bid % 6) * 64);
  gridbar(cnt, 36);
  small_body(As, Bs, t, W3, nullptr, 256, T, 384, o_ec, 360,
             360, 360, 256, (bid / 6) * 64, (bid % 6) * 64);
}

// ---------------------------------------------------------------------------
// Fused: blocks 0..511 -> gemv_p (HBM-bound Wp1 read);
//        blocks 512..767 -> g1 = relu(mc@Wg1^T+bg1) in LDS (direct-A, no
//        staging barriers), then o_zgeo = g1@Wg2^T+bg2 (rides under Wp1).
// ---------------------------------------------------------------------------
__global__ __launch_bounds__(512) void p_and_g1(
    const float* __restrict__ Wp1, const float* __restrict__ ec,
    const float* __restrict__ bp1, float* __restrict__ p,
    const float* __restrict__ mc, const __bf16* __restrict__ Wg1p,
    const float* __restrict__ bg1, const __bf16* __restrict__ Wg2p,
    const float* __restrict__ bg2, float* __restrict__ o_zgeo) {
  __shared__ __bf16 g1S[64][264];
  __shared__ float redw[8];
  int t = threadIdx.x;
  if (blockIdx.x < 512) {
    int row = blockIdx.x;
    const float4* w = (const float4*)(Wp1 + (size_t)row * 129600);
    const float4* e = (const float4*)ec;
    float s = 0.f;
    for (int i = t; i < 32400; i += 512) {
      float4 a = w[i], b = e[i];
      s += a.x * b.x + a.y * b.y + a.z * b.z + a.w * b.w;
    }
    for (int o = 32; o; o >>= 1) s += __shfl_down(s, o);
    if ((t & 63) == 0) redw[t >> 6] = s;
    __syncthreads();
    if (t == 0) {
      float tot = 0.f;
#pragma unroll
      for (int i = 0; i < 8; ++i) tot += redw[i];
      p[row] = fmaxf(tot + bp1[row], 0.f);
    }
  } else {
    int lane = t & 63, wid = t >> 6;
    int wr = wid >> 2, wc = wid & 3;
    int rowBase = (blockIdx.x - 512) * 64;
    int q4 = (lane >> 4) * 4;
    int kg = (lane >> 4) * 8;
    const float* a0p = mc + (size_t)(rowBase + wr * 32 + (lane & 15)) * 200;
    const float* a1p = a0p + (size_t)16 * 200;
    f32x4 acc[2][4] = {};
#pragma unroll
    for (int kt = 0; kt < 7; ++kt) {
      int k0 = kt * 32 + kg;
      bf16x8 a0, a1;
      if (k0 < 200) {
        float4 x0 = *(const float4*)(a0p + k0);
        float4 x1 = *(const float4*)(a0p + k0 + 4);
        float4 y0 = *(const float4*)(a1p + k0);
        float4 y1 = *(const float4*)(a1p + k0 + 4);
        a0 = cvt8(x0, x1);
        a1 = cvt8(y0, y1);
      } else {
#pragma unroll
        for (int e = 0; e < 8; ++e) { a0[e] = (__bf16)0.f; a1[e] = (__bf16)0.f; }
      }
#pragma unroll
      for (int n = 0; n < 4; ++n) {
        bf16x8 bv = ldB(Wg1p, kt, 16, wc * 4 + n, lane);
        acc[0][n] = mfma_bf16(a0, bv, acc[0][n]);
        acc[1][n] = mfma_bf16(a1, bv, acc[1][n]);
      }
    }
#pragma unroll
    for (int m = 0; m < 2; ++m)
#pragma unroll
      for (int n = 0; n < 4; ++n) {
        int col = wc * 64 + n * 16 + (lane & 15);
        float bb = bg1[col];
#pragma unroll
        for (int j = 0; j < 4; ++j) {
          int rl = wr * 32 + m * 16 + q4 + j;
          g1S[rl][col] = (__bf16)fmaxf(acc[m][n][j] + bb, 0.f);
        }
      }
    __syncthreads();
    // ---- zgeo = g1 @ Wg2^T + bg2 (N=128) ----
    f32x4 acc2[2][2] = {};
#pragma unroll
    for (int ks = 0; ks < 8; ++ks) {
      int arow = wr * 32 + (lane & 15), ak = ks * 32 + (lane >> 4) * 8;
      bf16x8 a0 = *reinterpret_cast<const bf16x8*>(&g1S[arow][ak]);
      bf16x8 a1 = *reinterpret_cast<const bf16x8*>(&g1S[arow + 16][ak]);
#pragma unroll
      for (int n = 0; n < 2; ++n) {
        bf16x8 bv = ldB(Wg2p, ks, 8, wc * 2 + n, lane);
        acc2[0][n] = mfma_bf16(a0, bv, acc2[0][n]);
        acc2[1][n] = mfma_bf16(a1, bv, acc2[1][n]);
      }
    }
#pragma unroll
    for (int m = 0; m < 2; ++m)
#pragma unroll
      for (int n = 0; n < 2; ++n) {
        int col = wc * 32 + n * 16 + (lane & 15);
        float bb = bg2[col];
#pragma unroll
        for (int j = 0; j < 4; ++j) {
          int row = rowBase + wr * 32 + m * 16 + q4 + j;
          o_zgeo[(size_t)row * 128 + col] = acc2[m][n][j] + bb;
        }
      }
  }
}

// ---------------------------------------------------------------------------
// Tail: znpi1 recomputed per block (Wp2 L2/L3-resident); zsum; normalize;
// r1 = relu(zn@Wr1^T+br1); recon = r1@Wr2^T+br2. Block = 64 rows, 8 waves.
// ---------------------------------------------------------------------------
__global__ __launch_bounds__(512) void mega_tail(
    const float* __restrict__ p, const float* __restrict__ Wp2,
    const float* __restrict__ bp2, const float* __restrict__ zgeo,
    const __bf16* __restrict__ Wr1p, const float* __restrict__ br1,
    const __bf16* __restrict__ Wr2p, const float* __restrict__ br2,
    float* __restrict__ o_znpi, float* __restrict__ o_zn,
    float* __restrict__ o_rec) {
  __shared__ __bf16 r1S[64][264];
  __shared__ __bf16 znS[64][136];
  __shared__ float znpiS[128];
  __shared__ float pS[512];
  int tid = threadIdx.x;
  int lane = tid & 63, wid = tid >> 6;
  int wr = wid >> 2, wc = wid & 3;
  int rowBase = blockIdx.x * 64;
  int q4 = (lane >> 4) * 4;
  pS[tid] = p[tid];
  __syncthreads();
  {  // znpi1 per block: col = tid>>2, 4-thread K-split
    int col = tid >> 2, q = tid & 3;
    const float4* w = (const float4*)(Wp2 + (size_t)col * 512 + q * 128);
    const float4* pv = (const float4*)(pS + q * 128);
    float s = 0.f;
#pragma unroll
    for (int i = 0; i < 32; ++i) {
      float4 a = w[i], b = pv[i];
      s += a.x * b.x + a.y * b.y + a.z * b.z + a.w * b.w;
    }
    s += __shfl_xor(s, 1);
    s += __shfl_xor(s, 2);
    if (q == 0) znpiS[col] = s + bp2[col];
  }
  __syncthreads();
  // ---- zsum + norm (32 lanes own one row) ----
  {
    int rg = tid >> 5;
    int c4 = (tid & 31) * 4;
    float4 zp = make_float4(znpiS[c4], znpiS[c4 + 1], znpiS[c4 + 2], znpiS[c4 + 3]);
#pragma unroll
    for (int ri = 0; ri < 4; ++ri) {
      int rl = rg + ri * 16;
      int row = rowBase + rl;
      float4 zg = *(const float4*)(zgeo + (size_t)row * 128 + c4);
      float4 zs = make_float4(zg.x + zp.x, zg.y + zp.y, zg.z + zp.z, zg.w + zp.w);
      *(float4*)(o_znpi + (size_t)row * 128 + c4) = zp;
      float ss = zs.x * zs.x + zs.y * zs.y + zs.z * zs.z + zs.w * zs.w;
      ss += __shfl_xor(ss, 1);
      ss += __shfl_xor(ss, 2);
      ss += __shfl_xor(ss, 4);
      ss += __shfl_xor(ss, 8);
      ss += __shfl_xor(ss, 16);
      float rn = 1.f / fmaxf(sqrtf(ss), 1e-12f);
      float4 zn = make_float4(zs.x * rn, zs.y * rn, zs.z * rn, zs.w * rn);
      *(float4*)(o_zn + (size_t)row * 128 + c4) = zn;
      bf16x4 znb;
      znb[0] = (__bf16)zn.x; znb[1] = (__bf16)zn.y;
      znb[2] = (__bf16)zn.z; znb[3] = (__bf16)zn.w;
      *reinterpret_cast<bf16x4*>(&znS[rl][c4]) = znb;
    }
  }
  __syncthreads();
  // ---- r1 = relu(zn@Wr1^T+br1) -> r1S ----
  {
    f32x4 acc[2][4] = {};
#pragma unroll
    for (int ks = 0; ks < 4; ++ks) {
      int arow = wr * 32 + (lane & 15), ak = ks * 32 + (lane >> 4) * 8;
      bf16x8 a0 = *reinterpret_cast<const bf16x8*>(&znS[arow][ak]);
      bf16x8 a1 = *reinterpret_cast<const bf16x8*>(&znS[arow + 16][ak]);
#pragma unroll
      for (int n = 0; n < 4; ++n) {
        bf16x8 bv = ldB(Wr1p, ks, 16, wc * 4 + n, lane);
        acc[0][n] = mfma_bf16(a0, bv, acc[0][n]);
        acc[1][n] = mfma_bf16(a1, bv, acc[1][n]);
      }
    }
#pragma unroll
    for (int m = 0; m < 2; ++m)
#pragma unroll
      for (int n = 0; n < 4; ++n) {
        int col = wc * 64 + n * 16 + (lane & 15);
        float bb = br1[col];
#pragma unroll
        for (int j = 0; j < 4; ++j) {
          int rl = wr * 32 + m * 16 + q4 + j;
          r1S[rl][col] = (__bf16)fmaxf(acc[m][n][j] + bb, 0.f);
        }
      }
  }
  __syncthreads();
  // ---- recon = r1@Wr2^T+br2 (N=384 padded, store cols<360) ----
  {
    f32x4 acc[2][6] = {};
#pragma unroll
    for (int ks = 0; ks < 8; ++ks) {
      int arow = wr * 32 + (lane & 15), ak = ks * 32 + (lane >> 4) * 8;
      bf16x8 a0 = *reinterpret_cast<const bf16x8*>(&r1S[arow][ak]);
      bf16x8 a1 = *reinterpret_cast<const bf16x8*>(&r1S[arow + 16][ak]);
#pragma unroll
      for (int n = 0; n < 6; ++n) {
        bf16x8 bv = ldB(Wr2p, ks, 24, wc * 6 + n, lane);
        acc[0][n] = mfma_bf16(a0, bv, acc[0][n]);
        acc[1][n] = mfma_bf16(a1, bv, acc[1][n]);
      }
    }
#pragma unroll
    for (int m = 0; m < 2; ++m)
#pragma unroll
      for (int n = 0; n < 6; ++n) {
        int col = wc * 96 + n * 16 + (lane & 15);
        if (col < 360) {
          float bb = br2[col];
#pragma unroll
          for (int j = 0; j < 4; ++j) {
            int rl = wr * 32 + m * 16 + q4 + j;
            o_rec[(size_t)(rowBase + rl) * 360 + col] = acc[m][n][j] + bb;
          }
        }
      }
  }
}

// ---------------------------------------------------------------------------
extern "C" void kernel_launch(void* const* d_in, const int* in_sizes, int n_in,
                              void* d_out, int out_size, void* d_ws,
                              size_t ws_size, hipStream_t stream) {
  (void)in_sizes; (void)n_in; (void)out_size; (void)ws_size;
  const float* x   = (const float*)d_in[0];
  const float* mc  = (const float*)d_in[2];
  const float* W1  = (const float*)d_in[3];  const float* b1  = (const float*)d_in[4];
  const float* W2  = (const float*)d_in[5];  const float* b2  = (const float*)d_in[6];
  const float* W3  = (const float*)d_in[7];
  const float* Wp1 = (const float*)d_in[9];  const float* bp1 = (const float*)d_in[10];
  const float* Wp2 = (const float*)d_in[11]; const float* bp2 = (const float*)d_in[12];
  const float* Wg1 = (const float*)d_in[13]; const float* bg1 = (const float*)d_in[14];
  const float* Wg2 = (const float*)d_in[15]; const float* bg2 = (const float*)d_in[16];
  const float* Wr1 = (const float*)d_in[17]; const float* br1 = (const float*)d_in[18];
  const float* Wr2 = (const float*)d_in[19]; const float* br2 = (const float*)d_in[20];

  float* out = (float*)d_out;
  float* o_znpi = out;                  // (B,128)
  float* o_zgeo = out + 2097152;        // (B,128)
  float* o_zn   = out + 4194304;        // (B,128)
  float* o_ec   = out + 6291456;        // (360,360)
  float* o_rec  = out + 6421056;        // (B,360)

  char* ws = (char*)d_ws;
  __bf16* m1T   = (__bf16*)(ws + 0);            // (256,16384)
  __bf16* m2T   = (__bf16*)(ws + 8388608);      // (256,16384)
  float*  G     = (float*)(ws + 16777216);      // 256x256
  float*  T     = (float*)(ws + 17039360);      // 256x384
  float*  p512  = (float*)(ws + 17432576);      // 512
  __bf16* W1p   = (__bf16*)(ws + 17434624);
  __bf16* W2p   = W1p  + (size_t)544 * 512;
  __bf16* Wg1p  = W2p  + (size_t)128 * 512;
  __bf16* Wg2p  = Wg1p + (size_t)112 * 512;
  __bf16* Wr1p  = Wg2p + (size_t)64 * 512;
  __bf16* Wr2p  = Wr1p + (size_t)64 * 512;
  int*    cnt   = (int*)(ws + 18565120);        // small_pair barrier counter

  pack_all<<<1136, 64, 0, stream>>>(W1, W2, Wg1, Wg2, Wr1, Wr2,
                                    W1p, W2p, Wg1p, Wg2p, Wr1p, Wr2p, G, cnt);
  h1h2_fused<<<512, 256, 0, stream>>>(x, W1p, b1, W2p, b2, m1T, m2T);
  gemm_masks<<<dim3(4, 4, 16), 256, 0, stream>>>(m2T, m1T, G);
  small_pair<<<36, 256, 0, stream>>>(W2, G, W1, W3, T, o_ec, cnt);
  p_and_g1<<<768, 512, 0, stream>>>(Wp1, o_ec, bp1, p512, mc, Wg1p, bg1,
                                    Wg2p, bg2, o_zgeo);
  mega_tail<<<256, 512, 0, stream>>>(p512, Wp2, bp2, o_zgeo, Wr1p, br1,
                                     Wr2p, br2, o_znpi, o_zn, o_rec);
}

// Round 7
// 248.070 us; speedup vs baseline: 1.0787x; 1.0787x over previous
//
#include <hip/hip_runtime.h>

typedef __bf16 bf16x8 __attribute__((ext_vector_type(8)));
typedef __bf16 bf16x4 __attribute__((ext_vector_type(4)));
typedef float  f32x4  __attribute__((ext_vector_type(4)));

__device__ __forceinline__ f32x4 mfma_bf16(bf16x8 a, bf16x8 b, f32x4 c) {
  return __builtin_amdgcn_mfma_f32_16x16x32_bf16(a, b, c, 0, 0, 0);
}
// Packed B-fragment load: Bp[((kt*NT+nt)*64+lane)*8 .. +7]
__device__ __forceinline__ bf16x8 ldB(const __bf16* Bp, int kt, int NT, int nt,
                                      int lane) {
  return *reinterpret_cast<const bf16x8*>(Bp + (((size_t)kt * NT + nt) * 64 + lane) * 8);
}

// ---------------------------------------------------------------------------
// All weight packs in ONE kernel + zero G. Segments by blockIdx.
// pack: out[((kt*NT+nt)*64+lane)*8+e] = W[nt*16+(lane&15)][kt*32+(lane>>4)*8+e]
// ---------------------------------------------------------------------------
__global__ void pack_all(const float* __restrict__ W1, const float* __restrict__ W2,
                         const float* __restrict__ Wg1, const float* __restrict__ Wg2,
                         const float* __restrict__ Wr1, const float* __restrict__ Wr2,
                         __bf16* __restrict__ W1p, __bf16* __restrict__ W2p,
                         __bf16* __restrict__ Wg1p, __bf16* __restrict__ Wg2p,
                         __bf16* __restrict__ Wr1p, __bf16* __restrict__ Wr2p,
                         float* __restrict__ G) {
  int bx = blockIdx.x;
  int lane = threadIdx.x;
  if (bx >= 1104) {  // zero G (256x256 f32): 32 blocks x 64 thr x 8 float4
    float4* g = (float4*)G;
    int base = (bx - 1104) * 512 + lane;
#pragma unroll
    for (int i = 0; i < 8; ++i) g[base + i * 64] = make_float4(0.f, 0.f, 0.f, 0.f);
    return;
  }
  const float* W; __bf16* out; int N, K, NT, local;
  if (bx < 544)      { W = W1;  out = W1p;  N = 256; K = 1080; NT = 16; local = bx; }
  else if (bx < 672) { W = W2;  out = W2p;  N = 256; K = 256;  NT = 16; local = bx - 544; }
  else if (bx < 784) { W = Wg1; out = Wg1p; N = 256; K = 200;  NT = 16; local = bx - 672; }
  else if (bx < 848) { W = Wg2; out = Wg2p; N = 128; K = 256;  NT = 8;  local = bx - 784; }
  else if (bx < 912) { W = Wr1; out = Wr1p; N = 256; K = 128;  NT = 16; local = bx - 848; }
  else               { W = Wr2; out = Wr2p; N = 360; K = 256;  NT = 24; local = bx - 912; }
  int nt = local % NT, kt = local / NT;
  int n = nt * 16 + (lane & 15);
  int k0 = kt * 32 + (lane >> 4) * 8;
  bf16x8 v;
#pragma unroll
  for (int e = 0; e < 8; ++e) {
    int k = k0 + e;
    float xv = (n < N && k < K) ? W[(size_t)n * K + k] : 0.f;
    v[e] = (__bf16)xv;
  }
  *reinterpret_cast<bf16x8*>(out + ((size_t)local * 64 + lane) * 8) = v;
}

// ---------------------------------------------------------------------------
// Fused surrogate: h1 = x@W1^T+b1 (K=1080, K_STEP=64 -> 17 barrier pairs),
// masks written TRANSPOSED: mT[col][row], col-major for streaming masks GEMM.
// relu(h1) stays in LDS; h2 = relu(h1)@W2^T+b2. Tile 32x256, 4 waves, grid 512.
// ---------------------------------------------------------------------------
__global__ __launch_bounds__(256) void h1h2_fused(
    const float* __restrict__ x, const __bf16* __restrict__ W1p,
    const float* __restrict__ b1, const __bf16* __restrict__ W2p,
    const float* __restrict__ b2, __bf16* __restrict__ m1T,
    __bf16* __restrict__ m2T) {
  __shared__ __bf16 Alds[32][68];    // 64-wide K-slab, stride 68 (~2-way banks)
  __shared__ __bf16 h1s[32][264];    // relu(h1)
  int tid = threadIdx.x;
  int lane = tid & 63, wid = tid >> 6;
  int rowBase = blockIdx.x * 32;
  int sr = tid >> 3, sc = (tid & 7) * 8;
  const float* aSrc = x + (size_t)(rowBase + sr) * 1080;
  f32x4 acc[2][4] = {};
  float4 c0a, c0b, c1a, c1b;
  auto LD = [&](int s, float4& a, float4& b) {
    int gk = s * 64 + sc;
    if (gk < 1080) {
      a = *(const float4*)(aSrc + gk);
      b = *(const float4*)(aSrc + gk + 4);
    } else {
      a = make_float4(0.f, 0.f, 0.f, 0.f);
      b = a;
    }
  };
  LD(0, c0a, c0b);
  LD(1, c1a, c1b);
  for (int s = 0; s < 17; ++s) {
    bf16x8 w8;
    w8[0] = (__bf16)c0a.x; w8[1] = (__bf16)c0a.y; w8[2] = (__bf16)c0a.z; w8[3] = (__bf16)c0a.w;
    w8[4] = (__bf16)c0b.x; w8[5] = (__bf16)c0b.y; w8[6] = (__bf16)c0b.z; w8[7] = (__bf16)c0b.w;
    *reinterpret_cast<bf16x8*>(&Alds[sr][sc]) = w8;
    __syncthreads();
    c0a = c1a; c0b = c1b;
    if (s + 2 < 17) LD(s + 2, c1a, c1b);
    int arow = lane & 15;
#pragma unroll
    for (int ks = 0; ks < 2; ++ks) {
      int ak = ks * 32 + (lane >> 4) * 8;
      bf16x8 a0 = *reinterpret_cast<const bf16x8*>(&Alds[arow][ak]);
      bf16x8 a1 = *reinterpret_cast<const bf16x8*>(&Alds[arow + 16][ak]);
      int kt = s * 2 + ks;
#pragma unroll
      for (int n = 0; n < 4; ++n) {
        bf16x8 bv = ldB(W1p, kt, 16, wid * 4 + n, lane);
        acc[0][n] = mfma_bf16(a0, bv, acc[0][n]);
        acc[1][n] = mfma_bf16(a1, bv, acc[1][n]);
      }
    }
    __syncthreads();
  }
  int q4 = (lane >> 4) * 4;
#pragma unroll
  for (int m = 0; m < 2; ++m)
#pragma unroll
    for (int n = 0; n < 4; ++n) {
      int col = wid * 64 + n * 16 + (lane & 15);
      float bb = b1[col];
#pragma unroll
      for (int j = 0; j < 4; ++j) {
        int rl = m * 16 + q4 + j;
        float h = acc[m][n][j] + bb;
        m1T[(size_t)col * 16384 + rowBase + rl] = (__bf16)(h > 0.f ? 1.f : 0.f);
        h1s[rl][col] = (__bf16)fmaxf(h, 0.f);
      }
    }
  __syncthreads();
  // ---- h2 phase: K=256 from LDS ----
  f32x4 acc2[2][4] = {};
#pragma unroll
  for (int ks = 0; ks < 8; ++ks) {
    int arow = lane & 15, ak = ks * 32 + (lane >> 4) * 8;
    bf16x8 a0 = *reinterpret_cast<const bf16x8*>(&h1s[arow][ak]);
    bf16x8 a1 = *reinterpret_cast<const bf16x8*>(&h1s[arow + 16][ak]);
#pragma unroll
    for (int n = 0; n < 4; ++n) {
      bf16x8 bv = ldB(W2p, ks, 16, wid * 4 + n, lane);
      acc2[0][n] = mfma_bf16(a0, bv, acc2[0][n]);
      acc2[1][n] = mfma_bf16(a1, bv, acc2[1][n]);
    }
  }
#pragma unroll
  for (int m = 0; m < 2; ++m)
#pragma unroll
    for (int n = 0; n < 4; ++n) {
      int col = wid * 64 + n * 16 + (lane & 15);
      float bb = b2[col];
#pragma unroll
      for (int j = 0; j < 4; ++j) {
        int rl = m * 16 + q4 + j;
        float h = acc2[m][n][j] + bb;
        m2T[(size_t)col * 16384 + rowBase + rl] = (__bf16)(h > 0.f ? 1.f : 0.f);
      }
    }
}

// ---------------------------------------------------------------------------
// Streaming masks GEMM: G += (1/B) * m2[chunk]^T @ m1[chunk].
// Transposed mask layout -> A/B fragments are direct contiguous bf16x8 loads.
// No LDS, no barriers. Partial tiles are exact dyadic rationals -> atomicAdd
// into G is exact & deterministic.
// ---------------------------------------------------------------------------
__global__ __launch_bounds__(256) void gemm_masks(
    const __bf16* __restrict__ m2T, const __bf16* __restrict__ m1T,
    float* __restrict__ G) {
  int tid = threadIdx.x;
  int lane = tid & 63, wid = tid >> 6;
  int wr = wid >> 1, wc = wid & 1;
  int ibase = blockIdx.x * 64, jbase = blockIdx.y * 64;
  size_t b0 = (size_t)blockIdx.z * 1024 + (lane >> 4) * 8;
  const __bf16* pa0 = m2T + (size_t)(ibase + wr * 32 + (lane & 15)) * 16384 + b0;
  const __bf16* pa1 = pa0 + (size_t)16 * 16384;
  const __bf16* pb0 = m1T + (size_t)(jbase + wc * 32 + (lane & 15)) * 16384 + b0;
  const __bf16* pb1 = pb0 + (size_t)16 * 16384;
  f32x4 acc[2][2] = {};
#pragma unroll 4
  for (int c = 0; c < 32; ++c) {
    bf16x8 a0 = *reinterpret_cast<const bf16x8*>(pa0 + c * 32);
    bf16x8 a1 = *reinterpret_cast<const bf16x8*>(pa1 + c * 32);
    bf16x8 bv0 = *reinterpret_cast<const bf16x8*>(pb0 + c * 32);
    bf16x8 bv1 = *reinterpret_cast<const bf16x8*>(pb1 + c * 32);
    acc[0][0] = mfma_bf16(a0, bv0, acc[0][0]);
    acc[0][1] = mfma_bf16(a0, bv1, acc[0][1]);
    acc[1][0] = mfma_bf16(a1, bv0, acc[1][0]);
    acc[1][1] = mfma_bf16(a1, bv1, acc[1][1]);
  }
  int q4 = (lane >> 4) * 4;
#pragma unroll
  for (int m = 0; m < 2; ++m)
#pragma unroll
    for (int n = 0; n < 2; ++n)
#pragma unroll
      for (int j = 0; j < 4; ++j) {
        int gi = ibase + wr * 32 + m * 16 + q4 + j;
        int gj = jbase + wc * 32 + n * 16 + (lane & 15);
        atomicAdd(&G[(size_t)gi * 256 + gj], acc[m][n][j] * (1.f / 16384.f));
      }
}

// ---------------------------------------------------------------------------
// Small f32 GEMM: C[MxN] = (A .* A2) @ B (row-major), 64x64 tile.
// ---------------------------------------------------------------------------
__global__ __launch_bounds__(256) void small_gemm(
    const float* __restrict__ A, const float* __restrict__ A2, int lda,
    const float* __restrict__ Bm, int ldb, float* __restrict__ C, int ldc,
    int M, int N, int K) {
  __shared__ float As[64][17];
  __shared__ float Bs[16][65];
  int t = threadIdx.x;
  int tx = t & 15, ty = t >> 4;
  int m0 = blockIdx.y * 64, n0 = blockIdx.x * 64;
  float acc[4][4] = {};
  for (int k0 = 0; k0 < K; k0 += 16) {
#pragma unroll
    for (int i = 0; i < 4; ++i) {
      int idx = t * 4 + i;
      int r = idx >> 4, kk = idx & 15;
      int gm = m0 + r, gk = k0 + kk;
      float v = (gm < M && gk < K) ? A[(size_t)gm * lda + gk] : 0.f;
      if (A2 && gm < M && gk < K) v *= A2[(size_t)gm * lda + gk];
      As[r][kk] = v;
      int kk2 = idx >> 6, cc = idx & 63;
      int gk2 = k0 + kk2, gn = n0 + cc;
      Bs[kk2][cc] = (gk2 < K && gn < N) ? Bm[(size_t)gk2 * ldb + gn] : 0.f;
    }
    __syncthreads();
#pragma unroll
    for (int kk = 0; kk < 16; ++kk)
#pragma unroll
      for (int i = 0; i < 4; ++i)
#pragma unroll
        for (int j = 0; j < 4; ++j)
          acc[i][j] += As[ty * 4 + i][kk] * Bs[kk][tx * 4 + j];
    __syncthreads();
  }
#pragma unroll
  for (int i = 0; i < 4; ++i)
#pragma unroll
    for (int j = 0; j < 4; ++j) {
      int gm = m0 + ty * 4 + i, gn = n0 + tx * 4 + j;
      if (gm < M && gn < N) C[(size_t)gm * ldc + gn] = acc[i][j];
    }
}

// ---------------------------------------------------------------------------
// Fused: blocks 0..511 -> gemv_p (HBM-bound Wp1 read);
//        blocks 512..767 -> g1 = relu(mc@Wg1^T+bg1) in LDS, then
//                           o_zgeo = g1@Wg2^T+bg2 (rides free under Wp1 stream).
// ---------------------------------------------------------------------------
__global__ __launch_bounds__(512) void p_and_g1(
    const float* __restrict__ Wp1, const float* __restrict__ ec,
    const float* __restrict__ bp1, float* __restrict__ p,
    const float* __restrict__ mc, const __bf16* __restrict__ Wg1p,
    const float* __restrict__ bg1, const __bf16* __restrict__ Wg2p,
    const float* __restrict__ bg2, float* __restrict__ o_zgeo) {
  __shared__ __bf16 Alds[64][40];
  __shared__ __bf16 g1S[64][264];
  __shared__ float redw[8];
  int t = threadIdx.x;
  if (blockIdx.x < 512) {
    int row = blockIdx.x;
    const float4* w = (const float4*)(Wp1 + (size_t)row * 129600);
    const float4* e = (const float4*)ec;
    float s = 0.f;
    for (int i = t; i < 32400; i += 512) {
      float4 a = w[i], b = e[i];
      s += a.x * b.x + a.y * b.y + a.z * b.z + a.w * b.w;
    }
    for (int o = 32; o; o >>= 1) s += __shfl_down(s, o);
    if ((t & 63) == 0) redw[t >> 6] = s;
    __syncthreads();
    if (t == 0) {
      float tot = 0.f;
#pragma unroll
      for (int i = 0; i < 8; ++i) tot += redw[i];
      p[row] = fmaxf(tot + bp1[row], 0.f);
    }
  } else {
    int lane = t & 63, wid = t >> 6;
    int wr = wid >> 2, wc = wid & 3;
    int rowBase = (blockIdx.x - 512) * 64;
    int sr = t >> 3, sc = (t & 7) * 4;
    const float* aSrc = mc + (size_t)(rowBase + sr) * 200;
    int q4 = (lane >> 4) * 4;
    f32x4 acc[2][4] = {};
    for (int kt = 0; kt < 7; ++kt) {
      int gk = kt * 32 + sc;
      bf16x4 w4;
      if (gk < 200) {
        float4 v = *(const float4*)(aSrc + gk);
        w4[0] = (__bf16)v.x; w4[1] = (__bf16)v.y;
        w4[2] = (__bf16)v.z; w4[3] = (__bf16)v.w;
      } else {
        w4[0] = w4[1] = w4[2] = w4[3] = (__bf16)0.f;
      }
      *reinterpret_cast<bf16x4*>(&Alds[sr][sc]) = w4;
      __syncthreads();
      int arow = wr * 32 + (lane & 15), ak = (lane >> 4) * 8;
      bf16x8 a0 = *reinterpret_cast<const bf16x8*>(&Alds[arow][ak]);
      bf16x8 a1 = *reinterpret_cast<const bf16x8*>(&Alds[arow + 16][ak]);
#pragma unroll
      for (int n = 0; n < 4; ++n) {
        bf16x8 bv = ldB(Wg1p, kt, 16, wc * 4 + n, lane);
        acc[0][n] = mfma_bf16(a0, bv, acc[0][n]);
        acc[1][n] = mfma_bf16(a1, bv, acc[1][n]);
      }
      __syncthreads();
    }
#pragma unroll
    for (int m = 0; m < 2; ++m)
#pragma unroll
      for (int n = 0; n < 4; ++n) {
        int col = wc * 64 + n * 16 + (lane & 15);
        float bb = bg1[col];
#pragma unroll
        for (int j = 0; j < 4; ++j) {
          int rl = wr * 32 + m * 16 + q4 + j;
          g1S[rl][col] = (__bf16)fmaxf(acc[m][n][j] + bb, 0.f);
        }
      }
    __syncthreads();
    // ---- zgeo = g1 @ Wg2^T + bg2 (N=128) ----
    f32x4 acc2[2][2] = {};
#pragma unroll
    for (int ks = 0; ks < 8; ++ks) {
      int arow = wr * 32 + (lane & 15), ak = ks * 32 + (lane >> 4) * 8;
      bf16x8 a0 = *reinterpret_cast<const bf16x8*>(&g1S[arow][ak]);
      bf16x8 a1 = *reinterpret_cast<const bf16x8*>(&g1S[arow + 16][ak]);
#pragma unroll
      for (int n = 0; n < 2; ++n) {
        bf16x8 bv = ldB(Wg2p, ks, 8, wc * 2 + n, lane);
        acc2[0][n] = mfma_bf16(a0, bv, acc2[0][n]);
        acc2[1][n] = mfma_bf16(a1, bv, acc2[1][n]);
      }
    }
#pragma unroll
    for (int m = 0; m < 2; ++m)
#pragma unroll
      for (int n = 0; n < 2; ++n) {
        int col = wc * 32 + n * 16 + (lane & 15);
        float bb = bg2[col];
#pragma unroll
        for (int j = 0; j < 4; ++j) {
          int row = rowBase + wr * 32 + m * 16 + q4 + j;
          o_zgeo[(size_t)row * 128 + col] = acc2[m][n][j] + bb;
        }
      }
  }
}

// znpi1[j] = bp2[j] + sum_k p[k]*Wp2[j*512+k]; 128 blocks x 64 threads
__global__ void gemv_z(const float* __restrict__ p, const float* __restrict__ Wp2,
                       const float* __restrict__ bp2, float* __restrict__ znpi1) {
  int j = blockIdx.x;
  int t = threadIdx.x;
  const float4* w = (const float4*)(Wp2 + (size_t)j * 512);
  const float4* pp = (const float4*)p;
  float4 a0 = w[t], b0 = pp[t];
  float4 a1 = w[t + 64], b1 = pp[t + 64];
  float s = a0.x * b0.x + a0.y * b0.y + a0.z * b0.z + a0.w * b0.w +
            a1.x * b1.x + a1.y * b1.y + a1.z * b1.z + a1.w * b1.w;
  for (int o = 32; o; o >>= 1) s += __shfl_down(s, o);
  if (t == 0) znpi1[j] = s + bp2[j];
}

// ---------------------------------------------------------------------------
// Tail: zsum = zgeo + znpi1; zn = normalize(zsum); r1 = relu(zn@Wr1^T+br1);
// recon = r1@Wr2^T+br2. One block = 64 rows, 8 waves. zn, r1 live in LDS.
// ---------------------------------------------------------------------------
__global__ __launch_bounds__(512) void mega_tail(
    const float* __restrict__ zgeo, const float* __restrict__ znpi1,
    const __bf16* __restrict__ Wr1p, const float* __restrict__ br1,
    const __bf16* __restrict__ Wr2p, const float* __restrict__ br2,
    float* __restrict__ o_znpi, float* __restrict__ o_zn,
    float* __restrict__ o_rec) {
  __shared__ __bf16 r1S[64][264];
  __shared__ __bf16 znS[64][136];
  __shared__ float znpiS[128];
  int tid = threadIdx.x;
  int lane = tid & 63, wid = tid >> 6;
  int wr = wid >> 2, wc = wid & 3;
  int rowBase = blockIdx.x * 64;
  int q4 = (lane >> 4) * 4;
  if (tid < 128) znpiS[tid] = znpi1[tid];
  __syncthreads();
  // ---- phase A: zsum + norm (thread group of 32 owns one row) ----
  {
    int rg = tid >> 5;          // 0..15
    int c4 = (tid & 31) * 4;    // 0..124
    float4 zp = make_float4(znpiS[c4], znpiS[c4 + 1], znpiS[c4 + 2], znpiS[c4 + 3]);
#pragma unroll
    for (int ri = 0; ri < 4; ++ri) {
      int rl = rg + ri * 16;
      int row = rowBase + rl;
      float4 zg = *(const float4*)(zgeo + (size_t)row * 128 + c4);
      float4 zs = make_float4(zg.x + zp.x, zg.y + zp.y, zg.z + zp.z, zg.w + zp.w);
      *(float4*)(o_znpi + (size_t)row * 128 + c4) = zp;
      float ss = zs.x * zs.x + zs.y * zs.y + zs.z * zs.z + zs.w * zs.w;
      ss += __shfl_xor(ss, 1);
      ss += __shfl_xor(ss, 2);
      ss += __shfl_xor(ss, 4);
      ss += __shfl_xor(ss, 8);
      ss += __shfl_xor(ss, 16);
      float rn = 1.f / fmaxf(sqrtf(ss), 1e-12f);
      float4 zn = make_float4(zs.x * rn, zs.y * rn, zs.z * rn, zs.w * rn);
      *(float4*)(o_zn + (size_t)row * 128 + c4) = zn;
      bf16x4 znb;
      znb[0] = (__bf16)zn.x; znb[1] = (__bf16)zn.y;
      znb[2] = (__bf16)zn.z; znb[3] = (__bf16)zn.w;
      *reinterpret_cast<bf16x4*>(&znS[rl][c4]) = znb;
    }
  }
  __syncthreads();
  // ---- phase B: r1 = relu(zn@Wr1^T+br1) -> r1S ----
  {
    f32x4 acc[2][4] = {};
#pragma unroll
    for (int ks = 0; ks < 4; ++ks) {
      int arow = wr * 32 + (lane & 15), ak = ks * 32 + (lane >> 4) * 8;
      bf16x8 a0 = *reinterpret_cast<const bf16x8*>(&znS[arow][ak]);
      bf16x8 a1 = *reinterpret_cast<const bf16x8*>(&znS[arow + 16][ak]);
#pragma unroll
      for (int n = 0; n < 4; ++n) {
        bf16x8 bv = ldB(Wr1p, ks, 16, wc * 4 + n, lane);
        acc[0][n] = mfma_bf16(a0, bv, acc[0][n]);
        acc[1][n] = mfma_bf16(a1, bv, acc[1][n]);
      }
    }
#pragma unroll
    for (int m = 0; m < 2; ++m)
#pragma unroll
      for (int n = 0; n < 4; ++n) {
        int col = wc * 64 + n * 16 + (lane & 15);
        float bb = br1[col];
#pragma unroll
        for (int j = 0; j < 4; ++j) {
          int rl = wr * 32 + m * 16 + q4 + j;
          r1S[rl][col] = (__bf16)fmaxf(acc[m][n][j] + bb, 0.f);
        }
      }
  }
  __syncthreads();
  // ---- phase C: recon = r1@Wr2^T+br2 (N=384 padded, store cols<360) ----
  {
    f32x4 acc[2][6] = {};
#pragma unroll
    for (int ks = 0; ks < 8; ++ks) {
      int arow = wr * 32 + (lane & 15), ak = ks * 32 + (lane >> 4) * 8;
      bf16x8 a0 = *reinterpret_cast<const bf16x8*>(&r1S[arow][ak]);
      bf16x8 a1 = *reinterpret_cast<const bf16x8*>(&r1S[arow + 16][ak]);
#pragma unroll
      for (int n = 0; n < 6; ++n) {
        bf16x8 bv = ldB(Wr2p, ks, 24, wc * 6 + n, lane);
        acc[0][n] = mfma_bf16(a0, bv, acc[0][n]);
        acc[1][n] = mfma_bf16(a1, bv, acc[1][n]);
      }
    }
#pragma unroll
    for (int m = 0; m < 2; ++m)
#pragma unroll
      for (int n = 0; n < 6; ++n) {
        int col = wc * 96 + n * 16 + (lane & 15);
        if (col < 360) {
          float bb = br2[col];
#pragma unroll
          for (int j = 0; j < 4; ++j) {
            int rl = wr * 32 + m * 16 + q4 + j;
            o_rec[(size_t)(rowBase + rl) * 360 + col] = acc[m][n][j] + bb;
          }
        }
      }
  }
}

// ---------------------------------------------------------------------------
extern "C" void kernel_launch(void* const* d_in, const int* in_sizes, int n_in,
                              void* d_out, int out_size, void* d_ws,
                              size_t ws_size, hipStream_t stream) {
  (void)in_sizes; (void)n_in; (void)out_size; (void)ws_size;
  const float* x   = (const float*)d_in[0];
  const float* mc  = (const float*)d_in[2];
  const float* W1  = (const float*)d_in[3];  const float* b1  = (const float*)d_in[4];
  const float* W2  = (const float*)d_in[5];  const float* b2  = (const float*)d_in[6];
  const float* W3  = (const float*)d_in[7];
  const float* Wp1 = (const float*)d_in[9];  const float* bp1 = (const float*)d_in[10];
  const float* Wp2 = (const float*)d_in[11]; const float* bp2 = (const float*)d_in[12];
  const float* Wg1 = (const float*)d_in[13]; const float* bg1 = (const float*)d_in[14];
  const float* Wg2 = (const float*)d_in[15]; const float* bg2 = (const float*)d_in[16];
  const float* Wr1 = (const float*)d_in[17]; const float* br1 = (const float*)d_in[18];
  const float* Wr2 = (const float*)d_in[19]; const float* br2 = (const float*)d_in[20];

  float* out = (float*)d_out;
  float* o_znpi = out;                  // (B,128)
  float* o_zgeo = out + 2097152;        // (B,128)
  float* o_zn   = out + 4194304;        // (B,128)
  float* o_ec   = out + 6291456;        // (360,360)
  float* o_rec  = out + 6421056;        // (B,360)

  char* ws = (char*)d_ws;
  __bf16* m1T   = (__bf16*)(ws + 0);            // (256,16384)
  __bf16* m2T   = (__bf16*)(ws + 8388608);      // (256,16384)
  float*  G     = (float*)(ws + 16777216);      // 256x256
  float*  T     = (float*)(ws + 17039360);      // 256x384
  float*  p512  = (float*)(ws + 17432576);      // 512
  float*  znpi1 = (float*)(ws + 17434624);      // 128
  __bf16* W1p   = (__bf16*)(ws + 17435648);
  __bf16* W2p   = W1p  + (size_t)544 * 512;
  __bf16* Wg1p  = W2p  + (size_t)128 * 512;
  __bf16* Wg2p  = Wg1p + (size_t)112 * 512;
  __bf16* Wr1p  = Wg2p + (size_t)64 * 512;
  __bf16* Wr2p  = Wr1p + (size_t)64 * 512;

  pack_all<<<1136, 64, 0, stream>>>(W1, W2, Wg1, Wg2, Wr1, Wr2,
                                    W1p, W2p, Wg1p, Wg2p, Wr1p, Wr2p, G);
  h1h2_fused<<<512, 256, 0, stream>>>(x, W1p, b1, W2p, b2, m1T, m2T);
  gemm_masks<<<dim3(4, 4, 16), 256, 0, stream>>>(m2T, m1T, G);
  small_gemm<<<dim3(6, 4), 256, 0, stream>>>(W2, G, 256, W1 + 720, 1080, T, 384,
                                             256, 360, 256);
  small_gemm<<<dim3(6, 6), 256, 0, stream>>>(W3, nullptr, 256, T, 384, o_ec, 360,
                                             360, 360, 256);
  p_and_g1<<<768, 512, 0, stream>>>(Wp1, o_ec, bp1, p512, mc, Wg1p, bg1,
                                    Wg2p, bg2, o_zgeo);
  gemv_z<<<128, 64, 0, stream>>>(p512, Wp2, bp2, znpi1);
  mega_tail<<<256, 512, 0, stream>>>(o_zgeo, znpi1, Wr1p, br1, Wr2p, br2,
                                     o_znpi, o_zn, o_rec);
}

// Round 8
// 221.577 us; speedup vs baseline: 1.2077x; 1.1196x over previous
//
#include <hip/hip_runtime.h>

typedef __bf16 bf16x8 __attribute__((ext_vector_type(8)));
typedef __bf16 bf16x4 __attribute__((ext_vector_type(4)));
typedef float  f32x4  __attribute__((ext_vector_type(4)));

__device__ __forceinline__ f32x4 mfma_bf16(bf16x8 a, bf16x8 b, f32x4 c) {
  return __builtin_amdgcn_mfma_f32_16x16x32_bf16(a, b, c, 0, 0, 0);
}
// Packed B-fragment load: Bp[((kt*NT+nt)*64+lane)*8 .. +7]
__device__ __forceinline__ bf16x8 ldB(const __bf16* Bp, int kt, int NT, int nt,
                                      int lane) {
  return *reinterpret_cast<const bf16x8*>(Bp + (((size_t)kt * NT + nt) * 64 + lane) * 8);
}

// Grid barrier -- ONLY for small grids (<=~150 blocks, light phases).
// R4 lesson: 512-block barriers with heavy phases cost 100s of us.
__device__ __forceinline__ void gridbar(int* cnt, int target) {
  __syncthreads();
  if (threadIdx.x == 0) {
    __threadfence();
    __hip_atomic_fetch_add(cnt, 1, __ATOMIC_RELEASE, __HIP_MEMORY_SCOPE_AGENT);
    while (__hip_atomic_load(cnt, __ATOMIC_RELAXED, __HIP_MEMORY_SCOPE_AGENT) < target)
      __builtin_amdgcn_s_sleep(4);
    __threadfence();
  }
  __syncthreads();
}

// ---------------------------------------------------------------------------
// All weight packs in ONE kernel + zero G + zero gridbar counter.
// ---------------------------------------------------------------------------
__global__ void pack_all(const float* __restrict__ W1, const float* __restrict__ W2,
                         const float* __restrict__ Wg1, const float* __restrict__ Wg2,
                         const float* __restrict__ Wr1, const float* __restrict__ Wr2,
                         __bf16* __restrict__ W1p, __bf16* __restrict__ W2p,
                         __bf16* __restrict__ Wg1p, __bf16* __restrict__ Wg2p,
                         __bf16* __restrict__ Wr1p, __bf16* __restrict__ Wr2p,
                         float* __restrict__ G, int* __restrict__ cnt) {
  int bx = blockIdx.x;
  int lane = threadIdx.x;
  if (bx >= 1104) {  // zero G (256x256 f32): 32 blocks x 64 thr x 8 float4
    if (bx == 1104 && lane == 0) cnt[0] = 0;
    float4* g = (float4*)G;
    int base = (bx - 1104) * 512 + lane;
#pragma unroll
    for (int i = 0; i < 8; ++i) g[base + i * 64] = make_float4(0.f, 0.f, 0.f, 0.f);
    return;
  }
  const float* W; __bf16* out; int N, K, NT, local;
  if (bx < 544)      { W = W1;  out = W1p;  N = 256; K = 1080; NT = 16; local = bx; }
  else if (bx < 672) { W = W2;  out = W2p;  N = 256; K = 256;  NT = 16; local = bx - 544; }
  else if (bx < 784) { W = Wg1; out = Wg1p; N = 256; K = 200;  NT = 16; local = bx - 672; }
  else if (bx < 848) { W = Wg2; out = Wg2p; N = 128; K = 256;  NT = 8;  local = bx - 784; }
  else if (bx < 912) { W = Wr1; out = Wr1p; N = 256; K = 128;  NT = 16; local = bx - 848; }
  else               { W = Wr2; out = Wr2p; N = 360; K = 256;  NT = 24; local = bx - 912; }
  int nt = local % NT, kt = local / NT;
  int n = nt * 16 + (lane & 15);
  int k0 = kt * 32 + (lane >> 4) * 8;
  bf16x8 v;
#pragma unroll
  for (int e = 0; e < 8; ++e) {
    int k = k0 + e;
    float xv = (n < N && k < K) ? W[(size_t)n * K + k] : 0.f;
    v[e] = (__bf16)xv;
  }
  *reinterpret_cast<bf16x8*>(out + ((size_t)local * 64 + lane) * 8) = v;
}

// ---------------------------------------------------------------------------
// Fused surrogate v3: tile 32x256, EIGHT waves (512 thr) -- wave (wr,wc) owns
// rows wr*16..+15, cols wc*64..+63. Grid 512 -> 2 blocks/CU -> 16 waves/CU
// (4/SIMD, double the old 4-wave version) so barrier drains and L2 B-fetch
// latency hide under co-resident waves. Per-output MFMA chain bit-identical.
// ---------------------------------------------------------------------------
__global__ __launch_bounds__(512) void h1h2_fused(
    const float* __restrict__ x, const __bf16* __restrict__ W1p,
    const float* __restrict__ b1, const __bf16* __restrict__ W2p,
    const float* __restrict__ b2, __bf16* __restrict__ m1T,
    __bf16* __restrict__ m2T) {
  __shared__ __bf16 Alds[32][68];    // 64-wide K-slab, stride 68 (~2-way banks)
  __shared__ __bf16 h1s[32][264];    // relu(h1)
  int tid = threadIdx.x;
  int lane = tid & 63, wid = tid >> 6;
  int wr = wid >> 2, wc = wid & 3;
  int rowBase = blockIdx.x * 32;
  int sr = tid >> 4, sc = (tid & 15) * 4;   // 32 rows x 16 thr x 4 floats
  const float* aSrc = x + (size_t)(rowBase + sr) * 1080;
  f32x4 acc[4] = {};
  float4 c0, c1;
  auto LD = [&](int s, float4& d) {
    int gk = s * 64 + sc;   // gk multiple of 4; gk<1080 => gk<=1076, safe float4
    d = (gk < 1080) ? *(const float4*)(aSrc + gk) : make_float4(0.f, 0.f, 0.f, 0.f);
  };
  LD(0, c0);
  LD(1, c1);
  for (int s = 0; s < 17; ++s) {
    bf16x4 w4;
    w4[0] = (__bf16)c0.x; w4[1] = (__bf16)c0.y;
    w4[2] = (__bf16)c0.z; w4[3] = (__bf16)c0.w;
    *reinterpret_cast<bf16x4*>(&Alds[sr][sc]) = w4;
    __syncthreads();
    c0 = c1;
    if (s + 2 < 17) LD(s + 2, c1);
    int arow = wr * 16 + (lane & 15);
#pragma unroll
    for (int ks = 0; ks < 2; ++ks) {
      int ak = ks * 32 + (lane >> 4) * 8;
      bf16x8 a0 = *reinterpret_cast<const bf16x8*>(&Alds[arow][ak]);
      int kt = s * 2 + ks;
#pragma unroll
      for (int n = 0; n < 4; ++n) {
        bf16x8 bv = ldB(W1p, kt, 16, wc * 4 + n, lane);
        acc[n] = mfma_bf16(a0, bv, acc[n]);
      }
    }
    __syncthreads();
  }
  int q4 = (lane >> 4) * 4;
#pragma unroll
  for (int n = 0; n < 4; ++n) {
    int col = wc * 64 + n * 16 + (lane & 15);
    float bb = b1[col];
#pragma unroll
    for (int j = 0; j < 4; ++j) {
      int rl = wr * 16 + q4 + j;
      float h = acc[n][j] + bb;
      m1T[(size_t)col * 16384 + rowBase + rl] = (__bf16)(h > 0.f ? 1.f : 0.f);
      h1s[rl][col] = (__bf16)fmaxf(h, 0.f);
    }
  }
  __syncthreads();
  // ---- h2 phase: K=256 from LDS ----
  f32x4 acc2[4] = {};
#pragma unroll
  for (int ks = 0; ks < 8; ++ks) {
    int arow = wr * 16 + (lane & 15), ak = ks * 32 + (lane >> 4) * 8;
    bf16x8 a0 = *reinterpret_cast<const bf16x8*>(&h1s[arow][ak]);
#pragma unroll
    for (int n = 0; n < 4; ++n) {
      bf16x8 bv = ldB(W2p, ks, 16, wc * 4 + n, lane);
      acc2[n] = mfma_bf16(a0, bv, acc2[n]);
    }
  }
#pragma unroll
  for (int n = 0; n < 4; ++n) {
    int col = wc * 64 + n * 16 + (lane & 15);
    float bb = b2[col];
#pragma unroll
    for (int j = 0; j < 4; ++j) {
      int rl = wr * 16 + q4 + j;
      float h = acc2[n][j] + bb;
      m2T[(size_t)col * 16384 + rowBase + rl] = (__bf16)(h > 0.f ? 1.f : 0.f);
    }
  }
}

// ---------------------------------------------------------------------------
// Streaming masks GEMM: G += (1/B) * m2[chunk]^T @ m1[chunk].
// Direct contiguous bf16x8 loads; no LDS/barriers. Exact dyadic atomics.
// ---------------------------------------------------------------------------
__global__ __launch_bounds__(256) void gemm_masks(
    const __bf16* __restrict__ m2T, const __bf16* __restrict__ m1T,
    float* __restrict__ G) {
  int tid = threadIdx.x;
  int lane = tid & 63, wid = tid >> 6;
  int wr = wid >> 1, wc = wid & 1;
  int ibase = blockIdx.x * 64, jbase = blockIdx.y * 64;
  size_t b0 = (size_t)blockIdx.z * 1024 + (lane >> 4) * 8;
  const __bf16* pa0 = m2T + (size_t)(ibase + wr * 32 + (lane & 15)) * 16384 + b0;
  const __bf16* pa1 = pa0 + (size_t)16 * 16384;
  const __bf16* pb0 = m1T + (size_t)(jbase + wc * 32 + (lane & 15)) * 16384 + b0;
  const __bf16* pb1 = pb0 + (size_t)16 * 16384;
  f32x4 acc[2][2] = {};
#pragma unroll 4
  for (int c = 0; c < 32; ++c) {
    bf16x8 a0 = *reinterpret_cast<const bf16x8*>(pa0 + c * 32);
    bf16x8 a1 = *reinterpret_cast<const bf16x8*>(pa1 + c * 32);
    bf16x8 bv0 = *reinterpret_cast<const bf16x8*>(pb0 + c * 32);
    bf16x8 bv1 = *reinterpret_cast<const bf16x8*>(pb1 + c * 32);
    acc[0][0] = mfma_bf16(a0, bv0, acc[0][0]);
    acc[0][1] = mfma_bf16(a0, bv1, acc[0][1]);
    acc[1][0] = mfma_bf16(a1, bv0, acc[1][0]);
    acc[1][1] = mfma_bf16(a1, bv1, acc[1][1]);
  }
  int q4 = (lane >> 4) * 4;
#pragma unroll
  for (int m = 0; m < 2; ++m)
#pragma unroll
    for (int n = 0; n < 2; ++n)
#pragma unroll
      for (int j = 0; j < 4; ++j) {
        int gi = ibase + wr * 32 + m * 16 + q4 + j;
        int gj = jbase + wc * 32 + n * 16 + (lane & 15);
        atomicAdd(&G[(size_t)gi * 256 + gj], acc[m][n][j] * (1.f / 16384.f));
      }
}

// ---------------------------------------------------------------------------
// 64x64-tile f32 GEMM body over K range [kBeg,kEnd) (multiples of 16, <=256).
// Optional A2 elementwise multiply; optional 4-chunk fixed-order B sum.
// ---------------------------------------------------------------------------
__device__ void small_body2(float (*As)[17], float (*Bs)[65], int t,
                            const float* __restrict__ A, const float* __restrict__ A2,
                            int lda, const float* __restrict__ Bm, int ldb,
                            bool sum4, size_t bStride, float* __restrict__ C,
                            int ldc, int M, int N, int kBeg, int kEnd,
                            int m0, int n0) {
  int tx = t & 15, ty = t >> 4;
  float acc[4][4] = {};
  for (int k0 = kBeg; k0 < kEnd; k0 += 16) {
#pragma unroll
    for (int i = 0; i < 4; ++i) {
      int idx = t * 4 + i;
      int r = idx >> 4, kk = idx & 15;
      int gm = m0 + r, gk = k0 + kk;
      float v = (gm < M) ? A[(size_t)gm * lda + gk] : 0.f;
      if (A2 && gm < M) v *= A2[(size_t)gm * lda + gk];
      As[r][kk] = v;
      int kk2 = idx >> 6, cc = idx & 63;
      int gk2 = k0 + kk2, gn = n0 + cc;
      float bv = 0.f;
      if (gn < N) {
        const float* bp = Bm + (size_t)gk2 * ldb + gn;
        bv = bp[0];
        if (sum4) bv = bv + bp[bStride] + bp[2 * bStride] + bp[3 * bStride];
      }
      Bs[kk2][cc] = bv;
    }
    __syncthreads();
#pragma unroll
    for (int kk = 0; kk < 16; ++kk)
#pragma unroll
      for (int i = 0; i < 4; ++i)
#pragma unroll
        for (int j = 0; j < 4; ++j)
          acc[i][j] += As[ty * 4 + i][kk] * Bs[kk][tx * 4 + j];
    __syncthreads();
  }
#pragma unroll
  for (int i = 0; i < 4; ++i)
#pragma unroll
    for (int j = 0; j < 4; ++j) {
      int gm = m0 + ty * 4 + i, gn = n0 + tx * 4 + j;
      if (gm < M && gn < N) C[(size_t)gm * ldc + gn] = acc[i][j];
    }
}

// ---------------------------------------------------------------------------
// ec chain, split-K, ONE kernel (144 blocks):
// P1 (96 blocks): Tpart[kc] = (W2.*G)[:,kc*64:+64] @ W1l[kc*64:+64,:]
// P2 (144 blocks): ecpart[kc] = W3[:,kc*64:+64] @ (sum Tpart)[kc*64:+64,:]
//   (B staged as fixed-order 4-chunk sum)
// P3: o_ec = fixed-order sum of ecpart. All sums deterministic.
// ---------------------------------------------------------------------------
__global__ __launch_bounds__(256) void small_split(
    const float* __restrict__ W2, const float* __restrict__ G,
    const float* __restrict__ W1, const float* __restrict__ W3,
    float* __restrict__ Tpart, float* __restrict__ ecpart,
    float* __restrict__ o_ec, int* __restrict__ cnt) {
  __shared__ float As[64][17];
  __shared__ float Bs[16][65];
  int t = threadIdx.x, bid = blockIdx.x;
  if (bid < 96) {
    int tile = bid >> 2, kc = bid & 3;
    small_body2(As, Bs, t, W2, G, 256, W1 + 720, 1080, false, 0,
                Tpart + (size_t)kc * 98304, 384, 256, 360,
                kc * 64, kc * 64 + 64, (tile / 6) * 64, (tile % 6) * 64);
  }
  gridbar(cnt, 144);
  {
    int tile = bid >> 2, kc = bid & 3;  // 144 = 36 tiles x 4 kc
    small_body2(As, Bs, t, W3, nullptr, 256, Tpart, 384, true, 98304,
                ecpart + (size_t)kc * 129600, 360, 360, 360,
                kc * 64, kc * 64 + 64, (tile / 6) * 64, (tile % 6) * 64);
  }
  gridbar(cnt, 288);
  {
    int base = bid * 900;  // 144 * 900 = 129600
    for (int i = t; i < 900; i += 256) {
      int idx = base + i;
      o_ec[idx] = ecpart[idx] + ecpart[129600 + idx] + ecpart[259200 + idx] +
                  ecpart[388800 + idx];
    }
  }
}

// ---------------------------------------------------------------------------
// Fused: blocks 0..511 -> gemv_p (HBM-bound Wp1 read);
//        blocks 512..767 -> g1 = relu(mc@Wg1^T+bg1) in LDS, then
//                           o_zgeo = g1@Wg2^T+bg2 (rides free under Wp1).
// ---------------------------------------------------------------------------
__global__ __launch_bounds__(512) void p_and_g1(
    const float* __restrict__ Wp1, const float* __restrict__ ec,
    const float* __restrict__ bp1, float* __restrict__ p,
    const float* __restrict__ mc, const __bf16* __restrict__ Wg1p,
    const float* __restrict__ bg1, const __bf16* __restrict__ Wg2p,
    const float* __restrict__ bg2, float* __restrict__ o_zgeo) {
  __shared__ __bf16 Alds[64][40];
  __shared__ __bf16 g1S[64][264];
  __shared__ float redw[8];
  int t = threadIdx.x;
  if (blockIdx.x < 512) {
    int row = blockIdx.x;
    const float4* w = (const float4*)(Wp1 + (size_t)row * 129600);
    const float4* e = (const float4*)ec;
    float s = 0.f;
    for (int i = t; i < 32400; i += 512) {
      float4 a = w[i], b = e[i];
      s += a.x * b.x + a.y * b.y + a.z * b.z + a.w * b.w;
    }
    for (int o = 32; o; o >>= 1) s += __shfl_down(s, o);
    if ((t & 63) == 0) redw[t >> 6] = s;
    __syncthreads();
    if (t == 0) {
      float tot = 0.f;
#pragma unroll
      for (int i = 0; i < 8; ++i) tot += redw[i];
      p[row] = fmaxf(tot + bp1[row], 0.f);
    }
  } else {
    int lane = t & 63, wid = t >> 6;
    int wr = wid >> 2, wc = wid & 3;
    int rowBase = (blockIdx.x - 512) * 64;
    int sr = t >> 3, sc = (t & 7) * 4;
    const float* aSrc = mc + (size_t)(rowBase + sr) * 200;
    int q4 = (lane >> 4) * 4;
    f32x4 acc[2][4] = {};
    for (int kt = 0; kt < 7; ++kt) {
      int gk = kt * 32 + sc;
      bf16x4 w4;
      if (gk < 200) {
        float4 v = *(const float4*)(aSrc + gk);
        w4[0] = (__bf16)v.x; w4[1] = (__bf16)v.y;
        w4[2] = (__bf16)v.z; w4[3] = (__bf16)v.w;
      } else {
        w4[0] = w4[1] = w4[2] = w4[3] = (__bf16)0.f;
      }
      *reinterpret_cast<bf16x4*>(&Alds[sr][sc]) = w4;
      __syncthreads();
      int arow = wr * 32 + (lane & 15), ak = (lane >> 4) * 8;
      bf16x8 a0 = *reinterpret_cast<const bf16x8*>(&Alds[arow][ak]);
      bf16x8 a1 = *reinterpret_cast<const bf16x8*>(&Alds[arow + 16][ak]);
#pragma unroll
      for (int n = 0; n < 4; ++n) {
        bf16x8 bv = ldB(Wg1p, kt, 16, wc * 4 + n, lane);
        acc[0][n] = mfma_bf16(a0, bv, acc[0][n]);
        acc[1][n] = mfma_bf16(a1, bv, acc[1][n]);
      }
      __syncthreads();
    }
#pragma unroll
    for (int m = 0; m < 2; ++m)
#pragma unroll
      for (int n = 0; n < 4; ++n) {
        int col = wc * 64 + n * 16 + (lane & 15);
        float bb = bg1[col];
#pragma unroll
        for (int j = 0; j < 4; ++j) {
          int rl = wr * 32 + m * 16 + q4 + j;
          g1S[rl][col] = (__bf16)fmaxf(acc[m][n][j] + bb, 0.f);
        }
      }
    __syncthreads();
    f32x4 acc2[2][2] = {};
#pragma unroll
    for (int ks = 0; ks < 8; ++ks) {
      int arow = wr * 32 + (lane & 15), ak = ks * 32 + (lane >> 4) * 8;
      bf16x8 a0 = *reinterpret_cast<const bf16x8*>(&g1S[arow][ak]);
      bf16x8 a1 = *reinterpret_cast<const bf16x8*>(&g1S[arow + 16][ak]);
#pragma unroll
      for (int n = 0; n < 2; ++n) {
        bf16x8 bv = ldB(Wg2p, ks, 8, wc * 2 + n, lane);
        acc2[0][n] = mfma_bf16(a0, bv, acc2[0][n]);
        acc2[1][n] = mfma_bf16(a1, bv, acc2[1][n]);
      }
    }
#pragma unroll
    for (int m = 0; m < 2; ++m)
#pragma unroll
      for (int n = 0; n < 2; ++n) {
        int col = wc * 32 + n * 16 + (lane & 15);
        float bb = bg2[col];
#pragma unroll
        for (int j = 0; j < 4; ++j) {
          int row = rowBase + wr * 32 + m * 16 + q4 + j;
          o_zgeo[(size_t)row * 128 + col] = acc2[m][n][j] + bb;
        }
      }
  }
}

// znpi1[j] = bp2[j] + sum_k p[k]*Wp2[j*512+k]; 128 blocks x 64 threads
__global__ void gemv_z(const float* __restrict__ p, const float* __restrict__ Wp2,
                       const float* __restrict__ bp2, float* __restrict__ znpi1) {
  int j = blockIdx.x;
  int t = threadIdx.x;
  const float4* w = (const float4*)(Wp2 + (size_t)j * 512);
  const float4* pp = (const float4*)p;
  float4 a0 = w[t], b0 = pp[t];
  float4 a1 = w[t + 64], b1 = pp[t + 64];
  float s = a0.x * b0.x + a0.y * b0.y + a0.z * b0.z + a0.w * b0.w +
            a1.x * b1.x + a1.y * b1.y + a1.z * b1.z + a1.w * b1.w;
  for (int o = 32; o; o >>= 1) s += __shfl_down(s, o);
  if (t == 0) znpi1[j] = s + bp2[j];
}

// ---------------------------------------------------------------------------
// Tail: zsum = zgeo + znpi1; zn = normalize(zsum); r1 = relu(zn@Wr1^T+br1);
// recon = r1@Wr2^T+br2. One block = 64 rows, 8 waves. zn, r1 live in LDS.
// ---------------------------------------------------------------------------
__global__ __launch_bounds__(512) void mega_tail(
    const float* __restrict__ zgeo, const float* __restrict__ znpi1,
    const __bf16* __restrict__ Wr1p, const float* __restrict__ br1,
    const __bf16* __restrict__ Wr2p, const float* __restrict__ br2,
    float* __restrict__ o_znpi, float* __restrict__ o_zn,
    float* __restrict__ o_rec) {
  __shared__ __bf16 r1S[64][264];
  __shared__ __bf16 znS[64][136];
  __shared__ float znpiS[128];
  int tid = threadIdx.x;
  int lane = tid & 63, wid = tid >> 6;
  int wr = wid >> 2, wc = wid & 3;
  int rowBase = blockIdx.x * 64;
  int q4 = (lane >> 4) * 4;
  if (tid < 128) znpiS[tid] = znpi1[tid];
  __syncthreads();
  {
    int rg = tid >> 5;
    int c4 = (tid & 31) * 4;
    float4 zp = make_float4(znpiS[c4], znpiS[c4 + 1], znpiS[c4 + 2], znpiS[c4 + 3]);
#pragma unroll
    for (int ri = 0; ri < 4; ++ri) {
      int rl = rg + ri * 16;
      int row = rowBase + rl;
      float4 zg = *(const float4*)(zgeo + (size_t)row * 128 + c4);
      float4 zs = make_float4(zg.x + zp.x, zg.y + zp.y, zg.z + zp.z, zg.w + zp.w);
      *(float4*)(o_znpi + (size_t)row * 128 + c4) = zp;
      float ss = zs.x * zs.x + zs.y * zs.y + zs.z * zs.z + zs.w * zs.w;
      ss += __shfl_xor(ss, 1);
      ss += __shfl_xor(ss, 2);
      ss += __shfl_xor(ss, 4);
      ss += __shfl_xor(ss, 8);
      ss += __shfl_xor(ss, 16);
      float rn = 1.f / fmaxf(sqrtf(ss), 1e-12f);
      float4 zn = make_float4(zs.x * rn, zs.y * rn, zs.z * rn, zs.w * rn);
      *(float4*)(o_zn + (size_t)row * 128 + c4) = zn;
      bf16x4 znb;
      znb[0] = (__bf16)zn.x; znb[1] = (__bf16)zn.y;
      znb[2] = (__bf16)zn.z; znb[3] = (__bf16)zn.w;
      *reinterpret_cast<bf16x4*>(&znS[rl][c4]) = znb;
    }
  }
  __syncthreads();
  {
    f32x4 acc[2][4] = {};
#pragma unroll
    for (int ks = 0; ks < 4; ++ks) {
      int arow = wr * 32 + (lane & 15), ak = ks * 32 + (lane >> 4) * 8;
      bf16x8 a0 = *reinterpret_cast<const bf16x8*>(&znS[arow][ak]);
      bf16x8 a1 = *reinterpret_cast<const bf16x8*>(&znS[arow + 16][ak]);
#pragma unroll
      for (int n = 0; n < 4; ++n) {
        bf16x8 bv = ldB(Wr1p, ks, 16, wc * 4 + n, lane);
        acc[0][n] = mfma_bf16(a0, bv, acc[0][n]);
        acc[1][n] = mfma_bf16(a1, bv, acc[1][n]);
      }
    }
#pragma unroll
    for (int m = 0; m < 2; ++m)
#pragma unroll
      for (int n = 0; n < 4; ++n) {
        int col = wc * 64 + n * 16 + (lane & 15);
        float bb = br1[col];
#pragma unroll
        for (int j = 0; j < 4; ++j) {
          int rl = wr * 32 + m * 16 + q4 + j;
          r1S[rl][col] = (__bf16)fmaxf(acc[m][n][j] + bb, 0.f);
        }
      }
  }
  __syncthreads();
  {
    f32x4 acc[2][6] = {};
#pragma unroll
    for (int ks = 0; ks < 8; ++ks) {
      int arow = wr * 32 + (lane & 15), ak = ks * 32 + (lane >> 4) * 8;
      bf16x8 a0 = *reinterpret_cast<const bf16x8*>(&r1S[arow][ak]);
      bf16x8 a1 = *reinterpret_cast<const bf16x8*>(&r1S[arow + 16][ak]);
#pragma unroll
      for (int n = 0; n < 6; ++n) {
        bf16x8 bv = ldB(Wr2p, ks, 24, wc * 6 + n, lane);
        acc[0][n] = mfma_bf16(a0, bv, acc[0][n]);
        acc[1][n] = mfma_bf16(a1, bv, acc[1][n]);
      }
    }
#pragma unroll
    for (int m = 0; m < 2; ++m)
#pragma unroll
      for (int n = 0; n < 6; ++n) {
        int col = wc * 96 + n * 16 + (lane & 15);
        if (col < 360) {
          float bb = br2[col];
#pragma unroll
          for (int j = 0; j < 4; ++j) {
            int rl = wr * 32 + m * 16 + q4 + j;
            o_rec[(size_t)(rowBase + rl) * 360 + col] = acc[m][n][j] + bb;
          }
        }
      }
  }
}

// ---------------------------------------------------------------------------
extern "C" void kernel_launch(void* const* d_in, const int* in_sizes, int n_in,
                              void* d_out, int out_size, void* d_ws,
                              size_t ws_size, hipStream_t stream) {
  (void)in_sizes; (void)n_in; (void)out_size; (void)ws_size;
  const float* x   = (const float*)d_in[0];
  const float* mc  = (const float*)d_in[2];
  const float* W1  = (const float*)d_in[3];  const float* b1  = (const float*)d_in[4];
  const float* W2  = (const float*)d_in[5];  const float* b2  = (const float*)d_in[6];
  const float* W3  = (const float*)d_in[7];
  const float* Wp1 = (const float*)d_in[9];  const float* bp1 = (const float*)d_in[10];
  const float* Wp2 = (const float*)d_in[11]; const float* bp2 = (const float*)d_in[12];
  const float* Wg1 = (const float*)d_in[13]; const float* bg1 = (const float*)d_in[14];
  const float* Wg2 = (const float*)d_in[15]; const float* bg2 = (const float*)d_in[16];
  const float* Wr1 = (const float*)d_in[17]; const float* br1 = (const float*)d_in[18];
  const float* Wr2 = (const float*)d_in[19]; const float* br2 = (const float*)d_in[20];

  float* out = (float*)d_out;
  float* o_znpi = out;                  // (B,128)
  float* o_zgeo = out + 2097152;        // (B,128)
  float* o_zn   = out + 4194304;        // (B,128)
  float* o_ec   = out + 6291456;        // (360,360)
  float* o_rec  = out + 6421056;        // (B,360)

  char* ws = (char*)d_ws;
  __bf16* m1T    = (__bf16*)(ws + 0);            // (256,16384)
  __bf16* m2T    = (__bf16*)(ws + 8388608);      // (256,16384)
  float*  G      = (float*)(ws + 16777216);      // 256x256
  float*  Tpart  = (float*)(ws + 17039360);      // 4 x 256 x 384
  float*  ecpart = (float*)(ws + 18612224);      // 4 x 360 x 360
  float*  p512   = (float*)(ws + 20686848);      // 512
  float*  znpi1  = (float*)(ws + 20688896);      // 128
  __bf16* W1p    = (__bf16*)(ws + 20689920);
  __bf16* W2p    = W1p  + (size_t)544 * 512;
  __bf16* Wg1p   = W2p  + (size_t)128 * 512;
  __bf16* Wg2p   = Wg1p + (size_t)112 * 512;
  __bf16* Wr1p   = Wg2p + (size_t)64 * 512;
  __bf16* Wr2p   = Wr1p + (size_t)64 * 512;
  int*    cnt    = (int*)(ws + 22020096);        // small_split barrier counter

  pack_all<<<1136, 64, 0, stream>>>(W1, W2, Wg1, Wg2, Wr1, Wr2,
                                    W1p, W2p, Wg1p, Wg2p, Wr1p, Wr2p, G, cnt);
  h1h2_fused<<<512, 512, 0, stream>>>(x, W1p, b1, W2p, b2, m1T, m2T);
  gemm_masks<<<dim3(4, 4, 16), 256, 0, stream>>>(m2T, m1T, G);
  small_split<<<144, 256, 0, stream>>>(W2, G, W1, W3, Tpart, ecpart, o_ec, cnt);
  p_and_g1<<<768, 512, 0, stream>>>(Wp1, o_ec, bp1, p512, mc, Wg1p, bg1,
                                    Wg2p, bg2, o_zgeo);
  gemv_z<<<128, 64, 0, stream>>>(p512, Wp2, bp2, znpi1);
  mega_tail<<<256, 512, 0, stream>>>(o_zgeo, znpi1, Wr1p, br1, Wr2p, br2,
                                     o_znpi, o_zn, o_rec);
}